// Round 11
// baseline (621.639 us; speedup 1.0000x reference)
//
#include <hip/hip_runtime.h>
#include <math.h>

#define NROWS 8192
#define DIM   512
#define NCLS  10
#define GT    4        // 128-wide tile grid (4x4)
#define GPAIR 10       // lower-triangle 128-tile pairs
#define NMAT  32

typedef __attribute__((ext_vector_type(8))) short bf16x8;
typedef __attribute__((ext_vector_type(4))) float f32x4;

__device__ __forceinline__ float rdlane(float v, int l) {
    return __int_as_float(__builtin_amdgcn_readlane(__float_as_int(v), l));
}

// fact 64x64 lower Cholesky by one wave: row-per-lane, readlane broadcasts.
__device__ __forceinline__ void fact64(float (*Dl)[68], float* dinv, float* ldm, int lane) {
    float row_[64];
    #pragma unroll
    for (int j = 0; j < 64; ++j) row_[j] = Dl[lane][j];
    float dval = 1.f;
    #pragma unroll
    for (int k = 0; k < 64; ++k) {
        float piv = rdlane(row_[k], k);
        float s = 1.0f / sqrtf(piv);
        float lik = row_[k] * s;
        dval = (lane == k) ? lik : dval;
        row_[k] = lik;
        #pragma unroll
        for (int j = k + 1; j < 64; ++j)
            row_[j] -= lik * rdlane(lik, j);
    }
    #pragma unroll
    for (int j = 0; j < 64; ++j) Dl[lane][j] = row_[j];
    dinv[lane] = 1.f / dval;
    float v = 2.f * logf(dval);
    #pragma unroll
    for (int off = 32; off > 0; off >>= 1) v += __shfl_down(v, off);
    if (lane == 0) atomicAdd(ldm, v);
}

// ---------------------------------------------------------------- counts/lists
__global__ __launch_bounds__(256) void k_count(const int* __restrict__ label,
                                               int* __restrict__ counts,
                                               int* __restrict__ lists) {
    __shared__ int hist[NCLS];
    __shared__ int base[NCLS];
    __shared__ int lofs[NCLS];
    int tid = threadIdx.x;
    int i = blockIdx.x * 256 + tid;
    if (tid < NCLS) { hist[tid] = 0; lofs[tid] = 0; }
    __syncthreads();
    int c = label[i];
    atomicAdd(&hist[c], 1);
    __syncthreads();
    if (tid < NCLS) base[tid] = atomicAdd(&counts[tid], hist[tid]);
    __syncthreads();
    int lpos = atomicAdd(&lofs[c], 1);
    lists[(size_t)c * NROWS + base[c] + lpos] = i;
}

// ---------------------------------------------------------------- per-class Grams (MFMA)
// G[tile 128x128] = Zti^T * Ztj, K = cnt rows, bf16 hi/lo 3-product (rel ~2^-16).
// LDS layout [col][k] bf16 with k-XOR swizzle — same proven pattern as chol's T.
__global__ __launch_bounds__(512) void k_gram(const float* __restrict__ Z,
                                              const float* __restrict__ Zb,
                                              const int* __restrict__ counts,
                                              const int* __restrict__ lists,
                                              float* __restrict__ G) {
    int pt = blockIdx.x;
    int c  = blockIdx.y;
    int tz = blockIdx.z;
    int ti = 0, tj = 0;
    { int p = pt;
      for (int r = 0; r < GT; ++r) { if (p <= r) { ti = r; tj = p; break; } p -= (r + 1); } }
    bool diag = (ti == tj);

    const float* __restrict__ src = tz ? Zb : Z;
    float* __restrict__ Gout = G + (((size_t)tz * NCLS + c) * GPAIR + pt) * 16384;
    int cnt = counts[c];
    const int* __restrict__ list = lists + (size_t)c * NROWS;

    __shared__ __align__(16) ushort Ahi[128][64];
    __shared__ __align__(16) ushort Alo[128][64];
    __shared__ __align__(16) ushort Bhi[128][64];
    __shared__ __align__(16) ushort Blo[128][64];

    int tid = threadIdx.x, wave = tid >> 6, lane = tid & 63;
    int lr = lane & 15, kb = lane >> 4;

    f32x4 acc[8];
    #pragma unroll
    for (int jt = 0; jt < 8; ++jt) acc[jt] = (f32x4){0.f, 0.f, 0.f, 0.f};

    int upw = diag ? 8 : 16;    // staging units per wave

    for (int base0 = 0; base0 < cnt; base0 += 64) {
        // stage 64 K-rows: unit = (op, colseg, kpair); lane owns a column
        #pragma unroll 1
        for (int q = 0; q < upw; ++q) {
            int u  = wave * upw + q;
            int op = (u >> 6) & 1;          // 0=A (ti), 1=B (tj); diag: always 0
            int cs = (u >> 5) & 1;
            int kp = u & 31;
            int col = cs * 64 + lane;
            int tcol = (op ? tj : ti) * 128 + col;
            int g0 = base0 + 2 * kp, g1 = g0 + 1;
            float v0 = 0.f, v1 = 0.f;
            if (g0 < cnt) v0 = src[(size_t)list[g0] * DIM + tcol];
            if (g1 < cnt) v1 = src[(size_t)list[g1] * DIM + tcol];
            uint h0 = __float_as_uint(v0) & 0xFFFF0000u;
            uint h1 = __float_as_uint(v1) & 0xFFFF0000u;
            uint l0 = __float_as_uint(v0 - __uint_as_float(h0));
            uint l1 = __float_as_uint(v1 - __uint_as_float(h1));
            int kidx = (2 * kp) ^ ((lane & 7) << 3);
            uint hv = (h0 >> 16) | h1;
            uint lv = (l0 >> 16) | (l1 & 0xFFFF0000u);
            if (op == 0) {
                *(uint*)&Ahi[col][kidx] = hv;
                *(uint*)&Alo[col][kidx] = lv;
            } else {
                *(uint*)&Bhi[col][kidx] = hv;
                *(uint*)&Blo[col][kidx] = lv;
            }
        }
        __syncthreads();

        const ushort (*__restrict__ BH)[64] = diag ? Ahi : Bhi;
        const ushort (*__restrict__ BL)[64] = diag ? Alo : Blo;
        int swz = (lr & 7) << 3;
        #pragma unroll
        for (int k0 = 0; k0 < 64; k0 += 32) {
            int kidx = (k0 + kb * 8) ^ swz;
            bf16x8 aH = *(const bf16x8*)&Ahi[wave * 16 + lr][kidx];
            bf16x8 aL = *(const bf16x8*)&Alo[wave * 16 + lr][kidx];
            #pragma unroll
            for (int jt = 0; jt < 8; ++jt) {
                bf16x8 bH = *(const bf16x8*)&BH[jt * 16 + lr][kidx];
                bf16x8 bL = *(const bf16x8*)&BL[jt * 16 + lr][kidx];
                acc[jt] = __builtin_amdgcn_mfma_f32_16x16x32_bf16(aH, bH, acc[jt], 0, 0, 0);
                acc[jt] = __builtin_amdgcn_mfma_f32_16x16x32_bf16(aH, bL, acc[jt], 0, 0, 0);
                acc[jt] = __builtin_amdgcn_mfma_f32_16x16x32_bf16(aL, bH, acc[jt], 0, 0, 0);
            }
        }
        __syncthreads();
    }

    // C/D layout (m89-verified): col = lane&15, row = (lane>>4)*4 + reg
    #pragma unroll
    for (int jt = 0; jt < 8; ++jt)
        #pragma unroll
        for (int rg = 0; rg < 4; ++rg)
            Gout[(size_t)(wave * 16 + kb * 4 + rg) * 128 + jt * 16 + lr] = acc[jt][rg];
}

// ---------------------------------------------------------------- assemble (lower tiles only)
__global__ __launch_bounds__(256) void k_assemble(const float* __restrict__ G,
                                                  const int* __restrict__ counts,
                                                  float* __restrict__ A) {
    int pt = blockIdx.x;
    int m  = blockIdx.y;
    int ti = 0, tj = 0;
    { int p = pt;
      for (int r = 0; r < GT; ++r) { if (p <= r) { ti = r; tj = p; break; } p -= (r + 1); } }

    const size_t TILE = 16384;
    const float* __restrict__ Gz  = G;
    const float* __restrict__ Gzb = G + (size_t)NCLS * GPAIR * TILE;
    float* __restrict__ Am = A + (size_t)m * DIM * DIM;
    int tid = threadIdx.x;

    int mode; int c; float sc;
    if (m < 10)      { mode = 0; c = m;      sc = 1024.f / ((float)counts[c] + 1e-8f); }
    else if (m < 20) { mode = 1; c = m - 10; sc = 1024.f / ((float)counts[c] + 1e-8f); }
    else if (m < 30) { mode = 2; c = m - 20; sc = 512.f / (float)counts[c]; }
    else             { mode = (m == 30) ? 3 : 4; c = 0; sc = 0.125f; }

    #pragma unroll 1
    for (int h = 0; h < 16; ++h) {
        int id = h * 256 + tid;
        int row = id >> 5, c4 = id & 31;
        size_t off = (size_t)row * 128 + c4 * 4;
        float4 g = make_float4(0.f, 0.f, 0.f, 0.f);
        if (mode == 0) {
            g = *(const float4*)&Gz[((size_t)c * GPAIR + pt) * TILE + off];
        } else if (mode == 1) {
            g = *(const float4*)&Gzb[((size_t)c * GPAIR + pt) * TILE + off];
        } else if (mode == 2) {
            float4 a = *(const float4*)&Gz [((size_t)c * GPAIR + pt) * TILE + off];
            float4 b = *(const float4*)&Gzb[((size_t)c * GPAIR + pt) * TILE + off];
            g.x = a.x + b.x; g.y = a.y + b.y; g.z = a.z + b.z; g.w = a.w + b.w;
        } else if (mode == 3) {
            for (int cc = 0; cc < NCLS; ++cc) {
                float4 t = *(const float4*)&Gz[((size_t)cc * GPAIR + pt) * TILE + off];
                g.x += t.x; g.y += t.y; g.z += t.z; g.w += t.w;
            }
        } else {
            for (int cc = 0; cc < NCLS; ++cc) {
                float4 t = *(const float4*)&Gzb[((size_t)cc * GPAIR + pt) * TILE + off];
                g.x += t.x; g.y += t.y; g.z += t.z; g.w += t.w;
            }
        }
        g.x *= sc; g.y *= sc; g.z *= sc; g.w *= sc;
        if (ti == tj) {
            int cb = c4 * 4;
            if (row == cb)     g.x += 1.f;
            if (row == cb + 1) g.y += 1.f;
            if (row == cb + 2) g.z += 1.f;
            if (row == cb + 3) g.w += 1.f;
        }
        *(float4*)&Am[(size_t)(ti * 128 + row) * DIM + tj * 128 + c4 * 4] = g;
    }
}

// ---------------------------------------------------------------- full Cholesky, ONE launch
// Pipelined: phase A = trsm (waves 1..K). Phase B: wave0 computes trailing tile(0,0)
// via MFMA, keeps it off global (orig - acc -> Dl), factorizes panel p+1; waves 1..7
// do the remaining syrk tiles (global RMW). 2 barriers/panel.
__global__ __launch_bounds__(512, 2) void k_chol(float* __restrict__ A,
                                                 float* __restrict__ ld) {
    int m = blockIdx.x;
    float* __restrict__ Am = A + (size_t)m * DIM * DIM;
    int tid = threadIdx.x;
    int wave = tid >> 6, lane = tid & 63;

    __shared__ float  Dl[64][68];
    __shared__ float  dinv[64];
    __shared__ ushort Thi[448][64];     // XOR-swizzled: idx ^= (row&7)<<3
    __shared__ ushort Tlo[448][64];

    for (int h = tid; h < 1024; h += 512) {
        int r = h >> 4, c4 = h & 15;
        *(float4*)&Dl[r][c4 * 4] = *(const float4*)&Am[(size_t)r * DIM + c4 * 4];
    }
    __syncthreads();
    if (wave == 0) fact64(Dl, dinv, &ld[m], lane);
    __syncthreads();

    #pragma unroll 1
    for (int p = 0; p < 7; ++p) {
        int col0 = p * 64, col1 = col0 + 64;
        int mt = DIM - col1;
        int K = mt >> 6;
        int npair = K * (K + 1) / 2;

        // ---- phase A: trsm (waves 1..K)
        int chunk = wave - 1;
        if (chunk >= 0 && chunk < K) {
            float Lreg[64];
            #pragma unroll
            for (int j4 = 0; j4 < 16; ++j4)
                *(float4*)&Lreg[j4 * 4] = *(const float4*)&Dl[lane][j4 * 4];
            float dv = dinv[lane];
            const float* __restrict__ Brow = Am + (size_t)(col1 + chunk * 64 + lane) * DIM + col0;
            float t[64];
            float4 bv;
            #pragma unroll
            for (int i = 0; i < 64; ++i) {
                if ((i & 3) == 0) bv = *(const float4*)&Brow[i];
                float a0 = (i & 3) == 0 ? bv.x : ((i & 3) == 1 ? bv.y : ((i & 3) == 2 ? bv.z : bv.w));
                float a1 = 0.f, a2 = 0.f, a3 = 0.f;
                int mm = 0;
                #pragma unroll
                for (; mm + 3 < i; mm += 4) {
                    a0 -= t[mm]     * rdlane(Lreg[mm],     i);
                    a1 -= t[mm + 1] * rdlane(Lreg[mm + 1], i);
                    a2 -= t[mm + 2] * rdlane(Lreg[mm + 2], i);
                    a3 -= t[mm + 3] * rdlane(Lreg[mm + 3], i);
                }
                #pragma unroll
                for (; mm < i; ++mm) a0 -= t[mm] * rdlane(Lreg[mm], i);
                t[i] = ((a0 + a1) + (a2 + a3)) * rdlane(dv, i);
            }
            int row = chunk * 64 + lane;
            int hsw = (row & 7) << 3;
            #pragma unroll
            for (int i = 0; i < 64; i += 2) {
                uint u0 = __float_as_uint(t[i]);
                float h0f = __uint_as_float(u0 & 0xFFFF0000u);
                uint l0 = __float_as_uint(t[i] - h0f);
                uint u1 = __float_as_uint(t[i + 1]);
                float h1f = __uint_as_float(u1 & 0xFFFF0000u);
                uint l1 = __float_as_uint(t[i + 1] - h1f);
                int idx = i ^ hsw;
                *(uint*)&Thi[row][idx] = (u0 >> 16) | (u1 & 0xFFFF0000u);
                *(uint*)&Tlo[row][idx] = (l0 >> 16) | (l1 & 0xFFFF0000u);
            }
        }
        __syncthreads();

        // ---- phase B
        int lr = lane & 15, kb = lane >> 4;
        if (wave == 0) {
            f32x4 acc[4][4];
            #pragma unroll
            for (int it = 0; it < 4; ++it)
                #pragma unroll
                for (int jt = 0; jt < 4; ++jt)
                    acc[it][jt] = (f32x4){0.f, 0.f, 0.f, 0.f};
            #pragma unroll
            for (int k0 = 0; k0 < 64; k0 += 32) {
                bf16x8 Ah[4], Al[4];
                int idx = (k0 + kb * 8) ^ ((lr & 7) << 3);
                #pragma unroll
                for (int it = 0; it < 4; ++it) {
                    int rowA = it * 16 + lr;
                    Ah[it] = *(const bf16x8*)&Thi[rowA][idx];
                    Al[it] = *(const bf16x8*)&Tlo[rowA][idx];
                }
                #pragma unroll
                for (int it = 0; it < 4; ++it)
                    #pragma unroll
                    for (int jt = 0; jt < 4; ++jt) {
                        acc[it][jt] = __builtin_amdgcn_mfma_f32_16x16x32_bf16(Ah[it], Ah[jt], acc[it][jt], 0, 0, 0);
                        acc[it][jt] = __builtin_amdgcn_mfma_f32_16x16x32_bf16(Ah[it], Al[jt], acc[it][jt], 0, 0, 0);
                        acc[it][jt] = __builtin_amdgcn_mfma_f32_16x16x32_bf16(Al[it], Ah[jt], acc[it][jt], 0, 0, 0);
                    }
            }
            #pragma unroll
            for (int it = 0; it < 4; ++it)
                #pragma unroll
                for (int jt = 0; jt < 4; ++jt)
                    #pragma unroll
                    for (int rg = 0; rg < 4; ++rg) {
                        int r = it * 16 + kb * 4 + rg;
                        int cg = jt * 16 + lr;
                        float orig = Am[(size_t)(col1 + r) * DIM + col1 + cg];
                        Dl[r][cg] = orig - acc[it][jt][rg];
                    }
            fact64(Dl, dinv, &ld[m], lane);
        } else {
            for (int tix = wave; tix < npair; tix += 7) {
                int a = 0, b = 0;
                { int q = tix;
                  for (int r0 = 0; r0 < 7; ++r0) { if (q <= r0) { a = r0; b = q; break; } q -= (r0 + 1); } }
                f32x4 acc[4][4];
                #pragma unroll
                for (int it = 0; it < 4; ++it)
                    #pragma unroll
                    for (int jt = 0; jt < 4; ++jt)
                        acc[it][jt] = (f32x4){0.f, 0.f, 0.f, 0.f};
                #pragma unroll
                for (int k0 = 0; k0 < 64; k0 += 32) {
                    bf16x8 Ah[4], Al[4], Bh[4], Bl[4];
                    int idx = (k0 + kb * 8) ^ ((lr & 7) << 3);
                    #pragma unroll
                    for (int it = 0; it < 4; ++it) {
                        int rowA = a * 64 + it * 16 + lr;
                        Ah[it] = *(const bf16x8*)&Thi[rowA][idx];
                        Al[it] = *(const bf16x8*)&Tlo[rowA][idx];
                        int rowB = b * 64 + it * 16 + lr;
                        Bh[it] = *(const bf16x8*)&Thi[rowB][idx];
                        Bl[it] = *(const bf16x8*)&Tlo[rowB][idx];
                    }
                    #pragma unroll
                    for (int it = 0; it < 4; ++it)
                        #pragma unroll
                        for (int jt = 0; jt < 4; ++jt) {
                            acc[it][jt] = __builtin_amdgcn_mfma_f32_16x16x32_bf16(Ah[it], Bh[jt], acc[it][jt], 0, 0, 0);
                            acc[it][jt] = __builtin_amdgcn_mfma_f32_16x16x32_bf16(Ah[it], Bl[jt], acc[it][jt], 0, 0, 0);
                            acc[it][jt] = __builtin_amdgcn_mfma_f32_16x16x32_bf16(Al[it], Bh[jt], acc[it][jt], 0, 0, 0);
                        }
                }
                #pragma unroll
                for (int it = 0; it < 4; ++it)
                    #pragma unroll
                    for (int jt = 0; jt < 4; ++jt)
                        #pragma unroll
                        for (int rg = 0; rg < 4; ++rg) {
                            int gi = col1 + a * 64 + it * 16 + kb * 4 + rg;
                            int gj = col1 + b * 64 + jt * 16 + lr;
                            Am[(size_t)gi * DIM + gj] -= acc[it][jt][rg];
                        }
            }
        }
        __syncthreads();
    }
}

// ---------------------------------------------------------------- finalize
__global__ void k_final(const float* __restrict__ ld,
                        const int* __restrict__ counts,
                        float* __restrict__ out) {
    if (threadIdx.x == 0 && blockIdx.x == 0) {
        float disc_z  = 0.5f * ld[30];
        float disc_zb = 0.5f * ld[31];
        float comp_z = 0.f, comp_zb = 0.f, sum_ldz = 0.f, sum_ldzb = 0.f, item = 0.f;
        for (int c = 0; c < NCLS; ++c) {
            float trPi = (float)counts[c] + 1e-8f;
            float s = trPi / (2.f * (float)NROWS);
            comp_z  += s * ld[c];
            comp_zb += s * ld[10 + c];
            sum_ldz  += ld[c];
            sum_ldzb += ld[10 + c];
            item += 0.5f * ld[20 + c];
        }
        float term3 = item - 0.25f * sum_ldz - 0.25f * sum_ldzb;
        float z_total  = -(disc_z - comp_z);
        float zb_total = -(disc_zb - comp_zb);
        float errD = -((disc_z - comp_z) + (disc_zb - comp_zb) + term3);
        out[0] = errD; out[1] = z_total; out[2] = zb_total; out[3] = term3;
    }
}

// ---------------------------------------------------------------- launch
extern "C" void kernel_launch(void* const* d_in, const int* in_sizes, int n_in,
                              void* d_out, int out_size, void* d_ws, size_t ws_size,
                              hipStream_t stream) {
    (void)in_sizes; (void)n_in; (void)out_size; (void)ws_size;
    const float* Z     = (const float*)d_in[0];
    const float* Zb    = (const float*)d_in[1];
    const int*   label = (const int*)d_in[2];

    char* ws = (char*)d_ws;
    int*   counts = (int*)ws;
    float* ld     = (float*)(ws + 64);
    int*   lists  = (int*)(ws + 256);
    float* G      = (float*)(ws + 256 + (size_t)NCLS * NROWS * 4);
    float* A      = G + (size_t)2 * NCLS * GPAIR * 16384;
    float* out    = (float*)d_out;

    hipMemsetAsync(ws, 0, 256, stream);
    k_count<<<NROWS / 256, 256, 0, stream>>>(label, counts, lists);
    k_gram<<<dim3(GPAIR, NCLS, 2), 512, 0, stream>>>(Z, Zb, counts, lists, G);
    k_assemble<<<dim3(GPAIR, NMAT), 256, 0, stream>>>(G, counts, A);
    k_chol<<<NMAT, 512, 0, stream>>>(A, ld);
    k_final<<<1, 64, 0, stream>>>(ld, counts, out);
}